// Round 4
// baseline (258.675 us; speedup 1.0000x reference)
//
#include <hip/hip_runtime.h>
#include <math.h>

#define N_NODES 50000
#define E_EDGES 800000
#define ET      (E_EDGES + N_NODES)   // edges + self loops
#define IN_DIM  128
#define HID     128
#define HEADS   8
#define C1      16
#define OUT_DIM 64
#define NEG_SLOPE 0.2f
#define LOG2E   1.4426950408889634f

#define TILE    8192
#define NT      ((ET + TILE - 1) / TILE)      // 104 tiles
#define NB      ((N_NODES + 255) / 256)       // 196 buckets of 256 nodes

#define PREP_BLOCKS 112
#define MEGA_A (NT + PREP_BLOCKS)             // 216
#define L1T_BLOCKS ((N_NODES + 63) / 64)      // 782
#define L1TA 391                              // l1-transform blocks in K2
#define L1TB (L1T_BLOCKS - L1TA)              // remainder in K3
#define FUSE_BLOCKS ((N_NODES + 31) / 32)     // 1563 (32 nodes/block)
#define L2_BLOCKS   ((N_NODES + 63) / 64)     // 782  (64 nodes/block)

typedef unsigned int uint32;
typedef __attribute__((ext_vector_type(8))) short bf16x8;
typedef __attribute__((ext_vector_type(4))) float f32x4;
typedef __attribute__((ext_vector_type(2))) float f32x2;

static __device__ __forceinline__ unsigned short f2bf(float f) {
    uint32 u = __float_as_uint(f);
    u += 0x7FFFu + ((u >> 16) & 1u);   // round to nearest even
    return (unsigned short)(u >> 16);
}

static __device__ __forceinline__ unsigned char f2fp8(float f) {
    int pk = __builtin_amdgcn_cvt_pk_fp8_f32(f, f, 0, false);   // RNE, OCP e4m3
    return (unsigned char)(pk & 0xFF);
}

// ---------------- Mega-kernel A: bucket_hist + prep_weights ----------------

__global__ __launch_bounds__(256) void prep_all(
        const int* __restrict__ dst, int* __restrict__ cnt,
        const float* __restrict__ W1, const float* __restrict__ as1,
        const float* __restrict__ ad1, const float* __restrict__ W2,
        const float* __restrict__ as2, const float* __restrict__ ad2,
        unsigned short* __restrict__ w1t, unsigned short* __restrict__ p1t,
        unsigned short* __restrict__ w2t, unsigned short* __restrict__ p2t) {
    __shared__ int hist[NB];
    int blk = blockIdx.x, t = threadIdx.x;
    if (blk < NT) {
        for (int b = t; b < NB; b += 256) hist[b] = 0;
        __syncthreads();
        int base = blk * TILE;
        #pragma unroll
        for (int it = 0; it < TILE / 256; ++it) {
            int i = base + it * 256 + t;
            if (i < ET) {
                int d = (i < E_EDGES) ? dst[i] : (i - E_EDGES);
                atomicAdd(&hist[d >> 8], 1);
            }
        }
        __syncthreads();
        for (int b = t; b < NB; b += 256) cnt[blk * NB + b] = hist[b];
    } else {
        int b = blk - NT;    // 0..111
        if (b < 64) {
            int i = b * 256 + t;                // n*128+k
            int n = i >> 7, k = i & 127;
            w1t[n * IN_DIM + k] = f2bf(W1[k * HID + n]);
        } else if (b < 96) {
            int i = (b - 64) * 256 + t;         // n*128+k, n<64
            int n = i >> 7, k = i & 127;
            w2t[n * HID + k] = f2bf(W2[k * OUT_DIM + n]);
        } else if (b < 104) {
            int i = (b - 96) * 256 + t;         // j*128+k, j<16
            int j = i >> 7, k = i & 127;
            int hh = j & 7;
            const float* a = (j < 8) ? as1 : ad1;
            float acc = 0.f;
            #pragma unroll
            for (int c = 0; c < C1; ++c)
                acc = fmaf(W1[k * HID + hh * C1 + c], a[hh * C1 + c], acc);
            p1t[j * IN_DIM + k] = f2bf(acc * LOG2E);
        } else {
            int i = (b - 104) * 256 + t;        // j*128+k, j<16
            int j = i >> 7, k = i & 127;
            if (j < 2) {
                const float* a = (j == 0) ? as2 : ad2;
                float acc = 0.f;
                #pragma unroll
                for (int c = 0; c < OUT_DIM; ++c)
                    acc = fmaf(W2[k * OUT_DIM + c], a[c], acc);
                p2t[j * HID + k] = f2bf(acc * LOG2E);
            } else {
                p2t[j * HID + k] = 0;
            }
        }
    }
}

// ---------------- layer-1 transform body (MFMA, LDS-free) — shared by K2/K3 ----------------

static __device__ __forceinline__ void l1_transform_body(
        int bb, int t,
        const float* __restrict__ x, const unsigned short* __restrict__ w1t,
        const unsigned short* __restrict__ p1t, unsigned char* __restrict__ h1f,
        float* __restrict__ a_src, float* __restrict__ a_dst) {
    int w = t >> 6, lane = t & 63;
    int l15 = lane & 15, quad = lane >> 4;
    int n0 = bb * 64 + w * 16;
    int mrow = n0 + l15;
    int mload = (mrow < N_NODES) ? mrow : (N_NODES - 1);

    bf16x8 af[4];
    #pragma unroll
    for (int s = 0; s < 4; ++s) {
        const float* xr = &x[(size_t)mload * IN_DIM + s * 32 + quad * 8];
        float4 lo = *(const float4*)xr;
        float4 hi = *(const float4*)(xr + 4);
        bf16x8 v;
        v[0] = (short)f2bf(lo.x); v[1] = (short)f2bf(lo.y);
        v[2] = (short)f2bf(lo.z); v[3] = (short)f2bf(lo.w);
        v[4] = (short)f2bf(hi.x); v[5] = (short)f2bf(hi.y);
        v[6] = (short)f2bf(hi.z); v[7] = (short)f2bf(hi.w);
        af[s] = v;
    }

    #pragma unroll
    for (int tt = 0; tt < 9; ++tt) {
        const unsigned short* Brow = (tt < 8) ? &w1t[(tt * 16 + l15) * IN_DIM]
                                              : &p1t[l15 * IN_DIM];
        f32x4 acc = {0.f, 0.f, 0.f, 0.f};
        #pragma unroll
        for (int s = 0; s < 4; ++s) {
            bf16x8 bf = *(const bf16x8*)&Brow[s * 32 + quad * 8];
            acc = __builtin_amdgcn_mfma_f32_16x16x32_bf16(af[s], bf, acc, 0, 0, 0);
        }
        int nodeb = n0 + quad * 4;
        if (tt < 8) {
            int ch = tt * 16 + l15;
            #pragma unroll
            for (int r = 0; r < 4; ++r)
                if (nodeb + r < N_NODES)
                    h1f[(size_t)(nodeb + r) * HID + ch] = f2fp8(acc[r]);
        } else {
            #pragma unroll
            for (int r = 0; r < 4; ++r) {
                if (nodeb + r < N_NODES) {
                    if (l15 < 8) a_src[(nodeb + r) * HEADS + l15] = acc[r];
                    else         a_dst[(nodeb + r) * HEADS + (l15 - 8)] = acc[r];
                }
            }
        }
    }
}

// ---------------- K2: bucket_scatter (scan fused) + l1-transform part A ----------------

__global__ __launch_bounds__(256) void scatter_l1ta(
        const int* __restrict__ src, const int* __restrict__ dst,
        const int* __restrict__ cnt, int* __restrict__ bucketStart,
        uint32* __restrict__ pairs,
        const float* __restrict__ x, const unsigned short* __restrict__ w1t,
        const unsigned short* __restrict__ p1t, unsigned char* __restrict__ h1f,
        float* __restrict__ a_src, float* __restrict__ a_dst) {
    __shared__ int lcur[NB];
    __shared__ int sscan[256];
    int t = threadIdx.x;
    if (blockIdx.x >= NT) {
        l1_transform_body(blockIdx.x - NT, t, x, w1t, p1t, h1f, a_src, a_dst);
        return;
    }
    int tile = blockIdx.x;

    int run = 0, total = 0;
    if (t < NB) {
        for (int k = 0; k < NT; ++k) {
            int c = cnt[k * NB + t];     // coalesced across t
            if (k < tile) run += c;
            total += c;
        }
    }
    sscan[t] = (t < NB) ? total : 0;
    __syncthreads();
    #pragma unroll
    for (int off = 1; off < 256; off <<= 1) {
        int add = (t >= off) ? sscan[t - off] : 0;
        __syncthreads();
        sscan[t] += add;
        __syncthreads();
    }
    int bstart = sscan[t] - total;       // exclusive prefix
    if (t < NB) {
        lcur[t] = bstart + run;
        if (tile == 0) bucketStart[t] = bstart;
    }
    if (tile == 0 && t == 0) bucketStart[NB] = ET;
    __syncthreads();

    int base = tile * TILE;
    #pragma unroll
    for (int it = 0; it < TILE / 256; ++it) {
        int i = base + it * 256 + t;
        if (i < ET) {
            int s, d;
            if (i < E_EDGES) { s = src[i]; d = dst[i]; }
            else             { s = d = i - E_EDGES; }
            int pos = atomicAdd(&lcur[d >> 8], 1);
            pairs[pos] = ((uint32)s << 8) | (uint32)(d & 255);
        }
    }
}

// ---------------- K3: bucket_build + l1-transform part B ----------------

__global__ __launch_bounds__(256) void bucket_l1tb(
        const uint32* __restrict__ pairs, const int* __restrict__ bucketStart,
        int* __restrict__ row_start, int* __restrict__ csr_src,
        const float* __restrict__ x, const unsigned short* __restrict__ w1t,
        const unsigned short* __restrict__ p1t, unsigned char* __restrict__ h1f,
        float* __restrict__ a_src, float* __restrict__ a_dst) {
    __shared__ int sdeg[256];
    __shared__ int sscan[256];
    int t = threadIdx.x;
    if (blockIdx.x >= NB) {
        l1_transform_body(blockIdx.x - NB + L1TA, t, x, w1t, p1t, h1f, a_src, a_dst);
        return;
    }
    int b = blockIdx.x;
    int beg = bucketStart[b], end = bucketStart[b + 1];
    sdeg[t] = 0;
    __syncthreads();
    for (int j = beg + t; j < end; j += 256)
        atomicAdd(&sdeg[pairs[j] & 255u], 1);
    __syncthreads();
    int v = sdeg[t];
    sscan[t] = v;
    __syncthreads();
    #pragma unroll
    for (int off = 1; off < 256; off <<= 1) {
        int add = (t >= off) ? sscan[t - off] : 0;
        __syncthreads();
        sscan[t] += add;
        __syncthreads();
    }
    int pos0 = beg + sscan[t] - v;   // exclusive prefix within bucket
    int n = b * 256 + t;
    if (n < N_NODES) row_start[n] = pos0;
    if (b == 0 && t == 0) row_start[N_NODES] = ET;
    __syncthreads();
    sscan[t] = pos0;                 // reuse as cursor
    __syncthreads();
    for (int j = beg + t; j < end; j += 256) {
        uint32 p = pairs[j];
        int pos = atomicAdd(&sscan[p & 255u], 1);
        csr_src[pos] = (int)(p >> 8);
    }
}

// ---------------- Fused: layer-1 aggregate + layer-2 transform ----------------
// 32-node tile / 4 waves; phase A: 8 lanes/node, uint4 (16-ch) fp8 gathers
// (one wave-load = 8 edges; lane == head). 8-deep batch + index prefetch.
// Phase B: 10 MFMA tile-tasks (2 tiles x {4 w2t + 1 p2t}) over 4 waves.

__global__ __launch_bounds__(256, 4) void l1agg_l2t(
        const unsigned char* __restrict__ h1f, const float* __restrict__ a_src,
        const float* __restrict__ a_dst, const int* __restrict__ row_start,
        const int* __restrict__ csr_src, const float* __restrict__ b1,
        const unsigned short* __restrict__ w2t, const unsigned short* __restrict__ p2t,
        unsigned char* __restrict__ h2f, float* __restrict__ a_src2,
        float* __restrict__ a_dst2) {
    __shared__ unsigned short ha[32][128];   // 8 KB, swizzled 16B granules
    __shared__ int sdeg32[32];
    __shared__ unsigned char perm[32];
    int t = threadIdx.x;
    int w = t >> 6;              // 0..3
    uint32 lane = t & 63;
    uint32 quarter = lane >> 4;  // phase B
    uint32 lane16 = lane & 15;   // phase B
    uint32 oct = lane >> 3;      // 0..7  phase A node slot
    uint32 lane8 = lane & 7;     // head index
    int n0blk = blockIdx.x * 32;

    if (t < 32) {
        int n = n0blk + t;
        int nc = (n < N_NODES) ? n : (N_NODES - 1);
        sdeg32[t] = row_start[nc + 1] - row_start[nc];
    }
    __syncthreads();
    if (t < 32) {
        int d = sdeg32[t];
        int r = 0;
        #pragma unroll
        for (int j = 0; j < 32; ++j) {
            int dj = sdeg32[j];
            r += (dj < d) || (dj == d && j < t);
        }
        perm[r] = (unsigned char)t;
    }
    __syncthreads();

    // ---------- phase A ----------
    {
        uint32 c0 = lane8 * 16u;     // 16 fp8 channels per lane
        uint32 h = lane8;            // head = c0 >> 4
        int n_local = (int)perm[w * 8 + (int)oct];
        int n = n0blk + n_local;
        int nc = (n < N_NODES) ? n : (N_NODES - 1);
        int beg = row_start[nc], end = row_start[nc + 1];
        int cnt = end - beg;
        int kmax = cnt;
        kmax = max(kmax, __shfl_xor(kmax, 8, 64));
        kmax = max(kmax, __shfl_xor(kmax, 16, 64));
        kmax = max(kmax, __shfl_xor(kmax, 32, 64));
        float adst = a_dst[nc * HEADS + h];
        float l = 0.f;
        float acc[16];
        #pragma unroll
        for (int i = 0; i < 16; ++i) acc[i] = 0.f;

        auto edge = [&](float e0, uint4 u0, bool live) {
            float e = e0 + adst;
            e = fmaxf(e, NEG_SLOPE * e);          // leaky relu (log2 domain)
            e = live ? e : -10000.f;              // masked lane -> p = 0
            float p = exp2f(e);
            l += p;
            f32x2 f01 = __builtin_amdgcn_cvt_pk_f32_fp8((int)u0.x, false);
            f32x2 f23 = __builtin_amdgcn_cvt_pk_f32_fp8((int)u0.x, true);
            f32x2 f45 = __builtin_amdgcn_cvt_pk_f32_fp8((int)u0.y, false);
            f32x2 f67 = __builtin_amdgcn_cvt_pk_f32_fp8((int)u0.y, true);
            f32x2 f89 = __builtin_amdgcn_cvt_pk_f32_fp8((int)u0.z, false);
            f32x2 fab = __builtin_amdgcn_cvt_pk_f32_fp8((int)u0.z, true);
            f32x2 fcd = __builtin_amdgcn_cvt_pk_f32_fp8((int)u0.w, false);
            f32x2 fef = __builtin_amdgcn_cvt_pk_f32_fp8((int)u0.w, true);
            acc[0]  = fmaf(p, f01[0], acc[0]);
            acc[1]  = fmaf(p, f01[1], acc[1]);
            acc[2]  = fmaf(p, f23[0], acc[2]);
            acc[3]  = fmaf(p, f23[1], acc[3]);
            acc[4]  = fmaf(p, f45[0], acc[4]);
            acc[5]  = fmaf(p, f45[1], acc[5]);
            acc[6]  = fmaf(p, f67[0], acc[6]);
            acc[7]  = fmaf(p, f67[1], acc[7]);
            acc[8]  = fmaf(p, f89[0], acc[8]);
            acc[9]  = fmaf(p, f89[1], acc[9]);
            acc[10] = fmaf(p, fab[0], acc[10]);
            acc[11] = fmaf(p, fab[1], acc[11]);
            acc[12] = fmaf(p, fcd[0], acc[12]);
            acc[13] = fmaf(p, fcd[1], acc[13]);
            acc[14] = fmaf(p, fef[0], acc[14]);
            acc[15] = fmaf(p, fef[1], acc[15]);
        };

        int k = 0;
        uint32 ssn[8];
        if (k + 8 <= kmax) {
            #pragma unroll
            for (int q = 0; q < 8; ++q) {
                int j = beg + q;
                int jc = (j < end) ? j : (end - 1);    // cnt >= 1 (self loop)
                ssn[q] = (uint32)csr_src[jc];
            }
        }
        for (; k + 8 <= kmax; k += 8) {
            uint32 ss[8]; float ee[8]; uint4 uu[8];
            #pragma unroll
            for (int q = 0; q < 8; ++q) ss[q] = ssn[q];
            #pragma unroll
            for (int q = 0; q < 8; ++q) ee[q] = a_src[ss[q] * 8u + h];
            #pragma unroll
            for (int q = 0; q < 8; ++q) uu[q] = *(const uint4*)&h1f[(ss[q] << 7) + c0];
            int kn = k + 8;
            if (kn + 8 <= kmax) {
                #pragma unroll
                for (int q = 0; q < 8; ++q) {
                    int j = beg + kn + q;
                    int jc = (j < end) ? j : (end - 1);
                    ssn[q] = (uint32)csr_src[jc];
                }
            }
            #pragma unroll
            for (int q = 0; q < 8; ++q) edge(ee[q], uu[q], k + q < cnt);
        }
        for (; k < kmax; k += 4) {
            uint32 ss[4]; float ee[4]; uint4 uu[4];
            #pragma unroll
            for (int q = 0; q < 4; ++q) {
                int j = beg + k + q;
                int jc = (j < end) ? j : (end - 1);
                ss[q] = (uint32)csr_src[jc];
            }
            #pragma unroll
            for (int q = 0; q < 4; ++q) ee[q] = a_src[ss[q] * 8u + h];
            #pragma unroll
            for (int q = 0; q < 4; ++q) uu[q] = *(const uint4*)&h1f[(ss[q] << 7) + c0];
            #pragma unroll
            for (int q = 0; q < 4; ++q) edge(ee[q], uu[q], k + q < cnt);
        }

        float inv = 1.f / (l + 1e-16f);
        float v[16];
        #pragma unroll
        for (int i = 0; i < 16; ++i) {
            float vi = acc[i] * inv + b1[c0 + i];
            v[i] = vi > 0.f ? vi : (__expf(vi) - 1.f);   // ELU
        }
        uint4 pk0, pk1;
        pk0.x = (uint32)f2bf(v[0])  | ((uint32)f2bf(v[1])  << 16);
        pk0.y = (uint32)f2bf(v[2])  | ((uint32)f2bf(v[3])  << 16);
        pk0.z = (uint32)f2bf(v[4])  | ((uint32)f2bf(v[5])  << 16);
        pk0.w = (uint32)f2bf(v[6])  | ((uint32)f2bf(v[7])  << 16);
        pk1.x = (uint32)f2bf(v[8])  | ((uint32)f2bf(v[9])  << 16);
        pk1.y = (uint32)f2bf(v[10]) | ((uint32)f2bf(v[11]) << 16);
        pk1.z = (uint32)f2bf(v[12]) | ((uint32)f2bf(v[13]) << 16);
        pk1.w = (uint32)f2bf(v[14]) | ((uint32)f2bf(v[15]) << 16);
        uint32 rl = (uint32)n_local & 15u;
        uint32 g0 = (2u * lane8 + 0u) ^ rl;   // swizzled 16B granule
        uint32 g1 = (2u * lane8 + 1u) ^ rl;
        *(uint4*)&ha[n_local][g0 * 8] = pk0;
        *(uint4*)&ha[n_local][g1 * 8] = pk1;
    }
    __syncthreads();

    // ---------- phase B: layer-2 transform from LDS ----------
    {
        int l15 = (int)lane16, quad = (int)quarter;

        #pragma unroll
        for (int pass = 0; pass < 3; ++pass) {
            int ti, tt;
            if (pass < 2) { ti = pass; tt = w; }
            else { if (w >= 2) break; ti = w; tt = 4; }

            int nloc = ti * 16 + l15;
            bf16x8 af[4];
            #pragma unroll
            for (int s = 0; s < 4; ++s) {
                uint32 g = (uint32)(s * 4 + quad) ^ (uint32)l15;
                af[s] = *(const bf16x8*)&ha[nloc][g * 8];
            }

            const unsigned short* Brow = (tt < 4) ? &w2t[(tt * 16 + l15) * HID]
                                                  : &p2t[l15 * HID];
            f32x4 acc = {0.f, 0.f, 0.f, 0.f};
            #pragma unroll
            for (int s = 0; s < 4; ++s) {
                bf16x8 bf = *(const bf16x8*)&Brow[s * 32 + quad * 8];
                acc = __builtin_amdgcn_mfma_f32_16x16x32_bf16(af[s], bf, acc, 0, 0, 0);
            }
            int nodeb = n0blk + ti * 16 + quad * 4;
            if (tt < 4) {
                int ch = tt * 16 + l15;
                #pragma unroll
                for (int r = 0; r < 4; ++r)
                    if (nodeb + r < N_NODES)
                        h2f[(size_t)(nodeb + r) * OUT_DIM + ch] = f2fp8(acc[r]);
            } else {
                #pragma unroll
                for (int r = 0; r < 4; ++r) {
                    if (nodeb + r < N_NODES) {
                        if (l15 == 0) a_src2[nodeb + r] = acc[r];
                        else if (l15 == 1) a_dst2[nodeb + r] = acc[r];
                    }
                }
            }
        }
    }
}

// ---------------- Layer 2: aggregate + log_softmax ----------------
// 4 lanes/node, 16 ch/lane (uint4 fp8 gathers): one wave-load = 16 edges.
// 64 nodes/block rank-sorted; 8-deep batch + index prefetch.

__global__ __launch_bounds__(256) void l2_aggregate(
        const unsigned char* __restrict__ h2f, const float* __restrict__ a_src2,
        const float* __restrict__ a_dst2, const int* __restrict__ row_start,
        const int* __restrict__ csr_src, const float* __restrict__ b2,
        float* __restrict__ out) {
    __shared__ int sdeg64[64];
    __shared__ unsigned char perm[64];
    int t = threadIdx.x;
    int w = t >> 6;
    uint32 lane = t & 63;
    uint32 lane4 = lane & 3;     // channel slot (16 ch each)
    uint32 nidx = lane >> 2;     // 0..15 node slot within wave
    int nbase = blockIdx.x * 64;
    if (t < 64) {
        int n = nbase + t;
        int nc = (n < N_NODES) ? n : (N_NODES - 1);
        sdeg64[t] = row_start[nc + 1] - row_start[nc];
    }
    __syncthreads();
    if (t < 64) {
        int d = sdeg64[t];
        int r = 0;
        #pragma unroll
        for (int j = 0; j < 64; ++j) {
            int dj = sdeg64[j];
            r += (dj < d) || (dj == d && j < t);
        }
        perm[r] = (unsigned char)t;
    }
    __syncthreads();
    int n = nbase + (int)perm[w * 16 + (int)nidx];
    int nc = (n < N_NODES) ? n : (N_NODES - 1);
    uint32 c0 = lane4 * 16u;
    int beg = row_start[nc], end = row_start[nc + 1];
    int cnt = end - beg;
    int kmax = cnt;
    kmax = max(kmax, __shfl_xor(kmax, 4, 64));
    kmax = max(kmax, __shfl_xor(kmax, 8, 64));
    kmax = max(kmax, __shfl_xor(kmax, 16, 64));
    kmax = max(kmax, __shfl_xor(kmax, 32, 64));
    float adst = a_dst2[nc];
    float l = 0.f;
    float acc[16];
    #pragma unroll
    for (int i = 0; i < 16; ++i) acc[i] = 0.f;

    auto edge2 = [&](float e0, uint4 u0, bool live) {
        float e = e0 + adst;
        e = fmaxf(e, NEG_SLOPE * e);
        e = live ? e : -10000.f;   // masked lane -> p = 0
        float p = exp2f(e);
        l += p;
        f32x2 f01 = __builtin_amdgcn_cvt_pk_f32_fp8((int)u0.x, false);
        f32x2 f23 = __builtin_amdgcn_cvt_pk_f32_fp8((int)u0.x, true);
        f32x2 f45 = __builtin_amdgcn_cvt_pk_f32_fp8((int)u0.y, false);
        f32x2 f67 = __builtin_amdgcn_cvt_pk_f32_fp8((int)u0.y, true);
        f32x2 f89 = __builtin_amdgcn_cvt_pk_f32_fp8((int)u0.z, false);
        f32x2 fab = __builtin_amdgcn_cvt_pk_f32_fp8((int)u0.z, true);
        f32x2 fcd = __builtin_amdgcn_cvt_pk_f32_fp8((int)u0.w, false);
        f32x2 fef = __builtin_amdgcn_cvt_pk_f32_fp8((int)u0.w, true);
        acc[0]  = fmaf(p, f01[0], acc[0]);
        acc[1]  = fmaf(p, f01[1], acc[1]);
        acc[2]  = fmaf(p, f23[0], acc[2]);
        acc[3]  = fmaf(p, f23[1], acc[3]);
        acc[4]  = fmaf(p, f45[0], acc[4]);
        acc[5]  = fmaf(p, f45[1], acc[5]);
        acc[6]  = fmaf(p, f67[0], acc[6]);
        acc[7]  = fmaf(p, f67[1], acc[7]);
        acc[8]  = fmaf(p, f89[0], acc[8]);
        acc[9]  = fmaf(p, f89[1], acc[9]);
        acc[10] = fmaf(p, fab[0], acc[10]);
        acc[11] = fmaf(p, fab[1], acc[11]);
        acc[12] = fmaf(p, fcd[0], acc[12]);
        acc[13] = fmaf(p, fcd[1], acc[13]);
        acc[14] = fmaf(p, fef[0], acc[14]);
        acc[15] = fmaf(p, fef[1], acc[15]);
    };

    int k = 0;
    uint32 ssn[8];
    if (k + 8 <= kmax) {
        #pragma unroll
        for (int q = 0; q < 8; ++q) {
            int j = beg + q;
            int jc = (j < end) ? j : (end - 1);
            ssn[q] = (uint32)csr_src[jc];
        }
    }
    for (; k + 8 <= kmax; k += 8) {
        uint32 ss[8]; float ee[8]; uint4 uu[8];
        #pragma unroll
        for (int q = 0; q < 8; ++q) ss[q] = ssn[q];
        #pragma unroll
        for (int q = 0; q < 8; ++q) ee[q] = a_src2[ss[q]];
        #pragma unroll
        for (int q = 0; q < 8; ++q) uu[q] = *(const uint4*)&h2f[(ss[q] << 6) + c0];
        int kn = k + 8;
        if (kn + 8 <= kmax) {
            #pragma unroll
            for (int q = 0; q < 8; ++q) {
                int j = beg + kn + q;
                int jc = (j < end) ? j : (end - 1);
                ssn[q] = (uint32)csr_src[jc];
            }
        }
        #pragma unroll
        for (int q = 0; q < 8; ++q) edge2(ee[q], uu[q], k + q < cnt);
    }
    for (; k < kmax; k += 4) {
        uint32 ss[4]; float ee[4]; uint4 uu[4];
        #pragma unroll
        for (int q = 0; q < 4; ++q) {
            int j = beg + k + q;
            int jc = (j < end) ? j : (end - 1);
            ss[q] = (uint32)csr_src[jc];
        }
        #pragma unroll
        for (int q = 0; q < 4; ++q) ee[q] = a_src2[ss[q]];
        #pragma unroll
        for (int q = 0; q < 4; ++q) uu[q] = *(const uint4*)&h2f[(ss[q] << 6) + c0];
        #pragma unroll
        for (int q = 0; q < 4; ++q) edge2(ee[q], uu[q], k + q < cnt);
    }

    float inv = 1.f / (l + 1e-16f);
    float o[16];
    #pragma unroll
    for (int i = 0; i < 16; ++i) o[i] = acc[i] * inv + b2[c0 + i];
    // log_softmax over 64 channels = 4 lanes x 16
    float mx = o[0];
    #pragma unroll
    for (int i = 1; i < 16; ++i) mx = fmaxf(mx, o[i]);
    mx = fmaxf(mx, __shfl_xor(mx, 1, 64));
    mx = fmaxf(mx, __shfl_xor(mx, 2, 64));
    float ex = 0.f;
    #pragma unroll
    for (int i = 0; i < 16; ++i) ex += __expf(o[i] - mx);
    ex += __shfl_xor(ex, 1, 64);
    ex += __shfl_xor(ex, 2, 64);
    float lse = mx + __logf(ex);
    if (n < N_NODES) {
        #pragma unroll
        for (int j = 0; j < 4; ++j) {
            float4 ov = make_float4(o[j*4+0] - lse, o[j*4+1] - lse,
                                    o[j*4+2] - lse, o[j*4+3] - lse);
            *(float4*)&out[(size_t)n * OUT_DIM + c0 + j * 4] = ov;
        }
    }
}

// ---------------- launch ----------------

extern "C" void kernel_launch(void* const* d_in, const int* in_sizes, int n_in,
                              void* d_out, int out_size, void* d_ws, size_t ws_size,
                              hipStream_t stream) {
    const float* x   = (const float*)d_in[0];
    const int*   ei  = (const int*)d_in[1];
    const float* W1  = (const float*)d_in[2];
    const float* as1 = (const float*)d_in[3];
    const float* ad1 = (const float*)d_in[4];
    const float* b1  = (const float*)d_in[5];
    const float* W2  = (const float*)d_in[6];
    const float* as2 = (const float*)d_in[7];
    const float* ad2 = (const float*)d_in[8];
    const float* b2  = (const float*)d_in[9];
    float* out = (float*)d_out;

    const int* src = ei;             // row 0
    const int* dst = ei + E_EDGES;   // row 1

    char* ws = (char*)d_ws;
    size_t off = 0;
    auto alloc = [&](size_t bytes) -> void* {
        void* p = ws + off;
        off += (bytes + 255) & ~size_t(255);
        return p;
    };
    unsigned char*  h1f    = (unsigned char*)alloc((size_t)N_NODES * HID);
    unsigned char*  h2f    = (unsigned char*)alloc((size_t)N_NODES * OUT_DIM);
    unsigned short* w1t    = (unsigned short*)alloc((size_t)HID * IN_DIM * 2);
    unsigned short* p1t    = (unsigned short*)alloc((size_t)16 * IN_DIM * 2);
    unsigned short* w2t    = (unsigned short*)alloc((size_t)OUT_DIM * HID * 2);
    unsigned short* p2t    = (unsigned short*)alloc((size_t)16 * HID * 2);
    float* a_src1    = (float*)alloc((size_t)N_NODES * HEADS * 4);
    float* a_dst1    = (float*)alloc((size_t)N_NODES * HEADS * 4);
    float* a_src2    = (float*)alloc((size_t)N_NODES * 4);
    float* a_dst2    = (float*)alloc((size_t)N_NODES * 4);
    int*   row_start = (int*)alloc((size_t)(N_NODES + 1) * 4);
    int*   csr_src   = (int*)alloc((size_t)ET * 4);
    uint32* pairs    = (uint32*)alloc((size_t)ET * 4);
    int*   cnt       = (int*)alloc((size_t)NB * NT * 4);
    int*   bucketStart = (int*)alloc((size_t)(NB + 1) * 4);

    prep_all<<<MEGA_A, 256, 0, stream>>>(dst, cnt, W1, as1, ad1,
                                         W2, as2, ad2, w1t, p1t, w2t, p2t);
    scatter_l1ta<<<NT + L1TA, 256, 0, stream>>>(src, dst, cnt, bucketStart, pairs,
                                                x, w1t, p1t, h1f, a_src1, a_dst1);
    bucket_l1tb<<<NB + L1TB, 256, 0, stream>>>(pairs, bucketStart, row_start, csr_src,
                                               x, w1t, p1t, h1f, a_src1, a_dst1);
    l1agg_l2t<<<FUSE_BLOCKS, 256, 0, stream>>>(h1f, a_src1, a_dst1, row_start, csr_src,
                                               b1, w2t, p2t, h2f, a_src2, a_dst2);
    l2_aggregate<<<L2_BLOCKS, 256, 0, stream>>>(h2f, a_src2, a_dst2, row_start,
                                                csr_src, b2, out);
}

// Round 5
// 188.202 us; speedup vs baseline: 1.3745x; 1.3745x over previous
//
#include <hip/hip_runtime.h>
#include <math.h>

#define N_NODES 50000
#define E_EDGES 800000
#define ET      (E_EDGES + N_NODES)   // edges + self loops
#define IN_DIM  128
#define HID     128
#define HEADS   8
#define C1      16
#define OUT_DIM 64
#define NEG_SLOPE 0.2f
#define LOG2E   1.4426950408889634f

#define TILE    8192
#define NT      ((ET + TILE - 1) / TILE)      // 104 tiles
#define NB      ((N_NODES + 255) / 256)       // 196 buckets of 256 nodes

#define PREP_BLOCKS 112
#define MEGA_A (NT + PREP_BLOCKS)             // 216
#define L1T_BLOCKS ((N_NODES + 63) / 64)      // 782
#define L1TA 391                              // l1-transform blocks in K2
#define L1TB (L1T_BLOCKS - L1TA)              // remainder in K3
#define FUSE_BLOCKS ((N_NODES + 15) / 16)     // 3125

typedef unsigned int uint32;
typedef __attribute__((ext_vector_type(8))) short bf16x8;
typedef __attribute__((ext_vector_type(4))) float f32x4;
typedef __attribute__((ext_vector_type(2))) float f32x2;

static __device__ __forceinline__ unsigned short f2bf(float f) {
    uint32 u = __float_as_uint(f);
    u += 0x7FFFu + ((u >> 16) & 1u);   // round to nearest even
    return (unsigned short)(u >> 16);
}

static __device__ __forceinline__ unsigned char f2fp8(float f) {
    int pk = __builtin_amdgcn_cvt_pk_fp8_f32(f, f, 0, false);   // RNE, OCP e4m3
    return (unsigned char)(pk & 0xFF);
}

// ---------------- Mega-kernel A: bucket_hist + prep_weights ----------------
// (x conversion is done inline in the l1 transform — no xb pass)

__global__ __launch_bounds__(256) void prep_all(
        const int* __restrict__ dst, int* __restrict__ cnt,
        const float* __restrict__ W1, const float* __restrict__ as1,
        const float* __restrict__ ad1, const float* __restrict__ W2,
        const float* __restrict__ as2, const float* __restrict__ ad2,
        unsigned short* __restrict__ w1t, unsigned short* __restrict__ p1t,
        unsigned short* __restrict__ w2t, unsigned short* __restrict__ p2t) {
    __shared__ int hist[NB];
    int blk = blockIdx.x, t = threadIdx.x;
    if (blk < NT) {
        for (int b = t; b < NB; b += 256) hist[b] = 0;
        __syncthreads();
        int base = blk * TILE;
        #pragma unroll
        for (int it = 0; it < TILE / 256; ++it) {
            int i = base + it * 256 + t;
            if (i < ET) {
                int d = (i < E_EDGES) ? dst[i] : (i - E_EDGES);
                atomicAdd(&hist[d >> 8], 1);
            }
        }
        __syncthreads();
        for (int b = t; b < NB; b += 256) cnt[blk * NB + b] = hist[b];
    } else {
        int b = blk - NT;    // 0..111
        if (b < 64) {
            int i = b * 256 + t;                // n*128+k
            int n = i >> 7, k = i & 127;
            w1t[n * IN_DIM + k] = f2bf(W1[k * HID + n]);
        } else if (b < 96) {
            int i = (b - 64) * 256 + t;         // n*128+k, n<64
            int n = i >> 7, k = i & 127;
            w2t[n * HID + k] = f2bf(W2[k * OUT_DIM + n]);
        } else if (b < 104) {
            int i = (b - 96) * 256 + t;         // j*128+k, j<16
            int j = i >> 7, k = i & 127;
            int hh = j & 7;
            const float* a = (j < 8) ? as1 : ad1;
            float acc = 0.f;
            #pragma unroll
            for (int c = 0; c < C1; ++c)
                acc = fmaf(W1[k * HID + hh * C1 + c], a[hh * C1 + c], acc);
            p1t[j * IN_DIM + k] = f2bf(acc * LOG2E);
        } else {
            int i = (b - 104) * 256 + t;        // j*128+k, j<16
            int j = i >> 7, k = i & 127;
            if (j < 2) {
                const float* a = (j == 0) ? as2 : ad2;
                float acc = 0.f;
                #pragma unroll
                for (int c = 0; c < OUT_DIM; ++c)
                    acc = fmaf(W2[k * OUT_DIM + c], a[c], acc);
                p2t[j * HID + k] = f2bf(acc * LOG2E);
            } else {
                p2t[j * HID + k] = 0;
            }
        }
    }
}

// ---------------- layer-1 transform body (MFMA, LDS-free) — shared by K2/K3 ----------------
// A-fragment: reads x in f32 and converts to bf16 in-register (same RNE).
// h1 payload stored as fp8 e4m3: 128 B/node.

static __device__ __forceinline__ void l1_transform_body(
        int bb, int t,
        const float* __restrict__ x, const unsigned short* __restrict__ w1t,
        const unsigned short* __restrict__ p1t, unsigned char* __restrict__ h1f,
        float* __restrict__ a_src, float* __restrict__ a_dst) {
    int w = t >> 6, lane = t & 63;
    int l15 = lane & 15, quad = lane >> 4;
    int n0 = bb * 64 + w * 16;
    int mrow = n0 + l15;
    int mload = (mrow < N_NODES) ? mrow : (N_NODES - 1);

    bf16x8 af[4];
    #pragma unroll
    for (int s = 0; s < 4; ++s) {
        const float* xr = &x[(size_t)mload * IN_DIM + s * 32 + quad * 8];
        float4 lo = *(const float4*)xr;
        float4 hi = *(const float4*)(xr + 4);
        bf16x8 v;
        v[0] = (short)f2bf(lo.x); v[1] = (short)f2bf(lo.y);
        v[2] = (short)f2bf(lo.z); v[3] = (short)f2bf(lo.w);
        v[4] = (short)f2bf(hi.x); v[5] = (short)f2bf(hi.y);
        v[6] = (short)f2bf(hi.z); v[7] = (short)f2bf(hi.w);
        af[s] = v;
    }

    #pragma unroll
    for (int tt = 0; tt < 9; ++tt) {
        const unsigned short* Brow = (tt < 8) ? &w1t[(tt * 16 + l15) * IN_DIM]
                                              : &p1t[l15 * IN_DIM];
        f32x4 acc = {0.f, 0.f, 0.f, 0.f};
        #pragma unroll
        for (int s = 0; s < 4; ++s) {
            bf16x8 bf = *(const bf16x8*)&Brow[s * 32 + quad * 8];
            acc = __builtin_amdgcn_mfma_f32_16x16x32_bf16(af[s], bf, acc, 0, 0, 0);
        }
        int nodeb = n0 + quad * 4;
        if (tt < 8) {
            int ch = tt * 16 + l15;
            #pragma unroll
            for (int r = 0; r < 4; ++r)
                if (nodeb + r < N_NODES)
                    h1f[(size_t)(nodeb + r) * HID + ch] = f2fp8(acc[r]);
        } else {
            #pragma unroll
            for (int r = 0; r < 4; ++r) {
                if (nodeb + r < N_NODES) {
                    if (l15 < 8) a_src[(nodeb + r) * HEADS + l15] = acc[r];
                    else         a_dst[(nodeb + r) * HEADS + (l15 - 8)] = acc[r];
                }
            }
        }
    }
}

// ---------------- K2: bucket_scatter (scan fused) + l1-transform part A ----------------

__global__ __launch_bounds__(256) void scatter_l1ta(
        const int* __restrict__ src, const int* __restrict__ dst,
        const int* __restrict__ cnt, int* __restrict__ bucketStart,
        uint32* __restrict__ pairs,
        const float* __restrict__ x, const unsigned short* __restrict__ w1t,
        const unsigned short* __restrict__ p1t, unsigned char* __restrict__ h1f,
        float* __restrict__ a_src, float* __restrict__ a_dst) {
    __shared__ int lcur[NB];
    __shared__ int sscan[256];
    int t = threadIdx.x;
    if (blockIdx.x >= NT) {
        l1_transform_body(blockIdx.x - NT, t, x, w1t, p1t, h1f, a_src, a_dst);
        return;
    }
    int tile = blockIdx.x;

    int run = 0, total = 0;
    if (t < NB) {
        for (int k = 0; k < NT; ++k) {
            int c = cnt[k * NB + t];     // coalesced across t
            if (k < tile) run += c;
            total += c;
        }
    }
    sscan[t] = (t < NB) ? total : 0;
    __syncthreads();
    #pragma unroll
    for (int off = 1; off < 256; off <<= 1) {
        int add = (t >= off) ? sscan[t - off] : 0;
        __syncthreads();
        sscan[t] += add;
        __syncthreads();
    }
    int bstart = sscan[t] - total;       // exclusive prefix
    if (t < NB) {
        lcur[t] = bstart + run;
        if (tile == 0) bucketStart[t] = bstart;
    }
    if (tile == 0 && t == 0) bucketStart[NB] = ET;
    __syncthreads();

    int base = tile * TILE;
    #pragma unroll
    for (int it = 0; it < TILE / 256; ++it) {
        int i = base + it * 256 + t;
        if (i < ET) {
            int s, d;
            if (i < E_EDGES) { s = src[i]; d = dst[i]; }
            else             { s = d = i - E_EDGES; }
            int pos = atomicAdd(&lcur[d >> 8], 1);
            pairs[pos] = ((uint32)s << 8) | (uint32)(d & 255);
        }
    }
}

// ---------------- K3: bucket_build + l1-transform part B ----------------

__global__ __launch_bounds__(256) void bucket_l1tb(
        const uint32* __restrict__ pairs, const int* __restrict__ bucketStart,
        int* __restrict__ row_start, int* __restrict__ csr_src,
        const float* __restrict__ x, const unsigned short* __restrict__ w1t,
        const unsigned short* __restrict__ p1t, unsigned char* __restrict__ h1f,
        float* __restrict__ a_src, float* __restrict__ a_dst) {
    __shared__ int sdeg[256];
    __shared__ int sscan[256];
    int t = threadIdx.x;
    if (blockIdx.x >= NB) {
        l1_transform_body(blockIdx.x - NB + L1TA, t, x, w1t, p1t, h1f, a_src, a_dst);
        return;
    }
    int b = blockIdx.x;
    int beg = bucketStart[b], end = bucketStart[b + 1];
    sdeg[t] = 0;
    __syncthreads();
    for (int j = beg + t; j < end; j += 256)
        atomicAdd(&sdeg[pairs[j] & 255u], 1);
    __syncthreads();
    int v = sdeg[t];
    sscan[t] = v;
    __syncthreads();
    #pragma unroll
    for (int off = 1; off < 256; off <<= 1) {
        int add = (t >= off) ? sscan[t - off] : 0;
        __syncthreads();
        sscan[t] += add;
        __syncthreads();
    }
    int pos0 = beg + sscan[t] - v;   // exclusive prefix within bucket
    int n = b * 256 + t;
    if (n < N_NODES) row_start[n] = pos0;
    if (b == 0 && t == 0) row_start[N_NODES] = ET;
    __syncthreads();
    sscan[t] = pos0;                 // reuse as cursor
    __syncthreads();
    for (int j = beg + t; j < end; j += 256) {
        uint32 p = pairs[j];
        int pos = atomicAdd(&sscan[p & 255u], 1);
        csr_src[pos] = (int)(p >> 8);
    }
}

// ---------------- Fused: layer-1 aggregate + layer-2 transform ----------------
// 256-thread block (4 waves) on a 16-node tile: phase A = ONE pass/wave
// (4 rank-adjacent nodes, 16 lanes/node, fp8 uint2 gathers, 8-deep batch,
// one-deep csr_src index prefetch — keeps live VGPRs <=128 for 4 waves/SIMD).
// Phase B: wave w does output tile tt=w (h2 stored fp8), wave 0 also tt=4.

__global__ __launch_bounds__(256, 4) void l1agg_l2t(
        const unsigned char* __restrict__ h1f, const float* __restrict__ a_src,
        const float* __restrict__ a_dst, const int* __restrict__ row_start,
        const int* __restrict__ csr_src, const float* __restrict__ b1,
        const unsigned short* __restrict__ w2t, const unsigned short* __restrict__ p2t,
        unsigned char* __restrict__ h2f, float* __restrict__ a_src2,
        float* __restrict__ a_dst2) {
    __shared__ unsigned short ha[16][128];   // 4 KB, swizzled granules
    __shared__ int sdeg16[16];
    __shared__ unsigned char perm[16];
    int t = threadIdx.x;
    int w = t >> 6;              // 0..3
    uint32 lane = t & 63;
    uint32 quarter = lane >> 4;
    uint32 lane16 = lane & 15;
    int n0blk = blockIdx.x * 16;

    // ---- degree-rank the 16 nodes (once per block) ----
    if (t < 16) {
        int n = n0blk + t;
        int nc = (n < N_NODES) ? n : (N_NODES - 1);
        sdeg16[t] = row_start[nc + 1] - row_start[nc];
    }
    __syncthreads();
    if (t < 16) {
        int d = sdeg16[t];
        int r = 0;
        #pragma unroll
        for (int j = 0; j < 16; ++j) {
            int dj = sdeg16[j];
            r += (dj < d) || (dj == d && j < t);
        }
        perm[r] = (unsigned char)t;
    }
    __syncthreads();

    // ---------- phase A: 4 waves x 4 nodes, one pass ----------
    {
        uint32 c0 = lane16 * 8u;     // 8 channels per lane (8 fp8 bytes)
        uint32 h = lane16 >> 1;      // head = c0 >> 4
        int n_local = (int)perm[w * 4 + (int)quarter];
        int n = n0blk + n_local;
        int nc = (n < N_NODES) ? n : (N_NODES - 1);
        int beg = row_start[nc], end = row_start[nc + 1];
        int cnt = end - beg;
        int kmax = cnt;
        kmax = max(kmax, __shfl_xor(kmax, 16, 64));
        kmax = max(kmax, __shfl_xor(kmax, 32, 64));
        float adst = a_dst[nc * HEADS + h];
        float l = 0.f;
        float a0 = 0.f, a1 = 0.f, a2 = 0.f, a3 = 0.f;
        float a4 = 0.f, a5 = 0.f, a6 = 0.f, a7 = 0.f;

        auto edge = [&](float e0, uint2 u0, bool live) {
            float e = e0 + adst;
            e = fmaxf(e, NEG_SLOPE * e);          // leaky relu (log2 domain)
            e = live ? e : -10000.f;              // masked lane -> p = 0
            float p = exp2f(e);
            l += p;
            f32x2 f01 = __builtin_amdgcn_cvt_pk_f32_fp8((int)u0.x, false);
            f32x2 f23 = __builtin_amdgcn_cvt_pk_f32_fp8((int)u0.x, true);
            f32x2 f45 = __builtin_amdgcn_cvt_pk_f32_fp8((int)u0.y, false);
            f32x2 f67 = __builtin_amdgcn_cvt_pk_f32_fp8((int)u0.y, true);
            a0 = fmaf(p, f01[0], a0);
            a1 = fmaf(p, f01[1], a1);
            a2 = fmaf(p, f23[0], a2);
            a3 = fmaf(p, f23[1], a3);
            a4 = fmaf(p, f45[0], a4);
            a5 = fmaf(p, f45[1], a5);
            a6 = fmaf(p, f67[0], a6);
            a7 = fmaf(p, f67[1], a7);
        };

        int k = 0;
        uint32 ssn[8];
        if (k + 8 <= kmax) {
            #pragma unroll
            for (int q = 0; q < 8; ++q) {
                int j = beg + q;
                int jc = (j < end) ? j : (end - 1);    // cnt >= 1 (self loop)
                ssn[q] = (uint32)csr_src[jc];
            }
        }
        for (; k + 8 <= kmax; k += 8) {
            uint32 ss[8]; float ee[8]; uint2 uu[8];
            #pragma unroll
            for (int q = 0; q < 8; ++q) ss[q] = ssn[q];
            // indices already in regs -> gathers issue immediately
            #pragma unroll
            for (int q = 0; q < 8; ++q) ee[q] = a_src[ss[q] * 8u + h];
            #pragma unroll
            for (int q = 0; q < 8; ++q) uu[q] = *(const uint2*)&h1f[(ss[q] << 7) + c0];
            // prefetch next batch's indices under this batch's compute
            int kn = k + 8;
            if (kn + 8 <= kmax) {
                #pragma unroll
                for (int q = 0; q < 8; ++q) {
                    int j = beg + kn + q;
                    int jc = (j < end) ? j : (end - 1);
                    ssn[q] = (uint32)csr_src[jc];
                }
            }
            #pragma unroll
            for (int q = 0; q < 8; ++q) edge(ee[q], uu[q], k + q < cnt);
        }
        for (; k < kmax; k += 4) {
            uint32 ss[4]; float ee[4]; uint2 uu[4];
            #pragma unroll
            for (int q = 0; q < 4; ++q) {
                int j = beg + k + q;
                int jc = (j < end) ? j : (end - 1);
                ss[q] = (uint32)csr_src[jc];
            }
            #pragma unroll
            for (int q = 0; q < 4; ++q) ee[q] = a_src[ss[q] * 8u + h];
            #pragma unroll
            for (int q = 0; q < 4; ++q) uu[q] = *(const uint2*)&h1f[(ss[q] << 7) + c0];
            #pragma unroll
            for (int q = 0; q < 4; ++q) edge(ee[q], uu[q], k + q < cnt);
        }

        float inv = 1.f / (l + 1e-16f);
        float v0 = a0 * inv + b1[c0 + 0];
        float v1 = a1 * inv + b1[c0 + 1];
        float v2 = a2 * inv + b1[c0 + 2];
        float v3 = a3 * inv + b1[c0 + 3];
        float v4 = a4 * inv + b1[c0 + 4];
        float v5 = a5 * inv + b1[c0 + 5];
        float v6 = a6 * inv + b1[c0 + 6];
        float v7 = a7 * inv + b1[c0 + 7];
        v0 = v0 > 0.f ? v0 : (__expf(v0) - 1.f);   // ELU
        v1 = v1 > 0.f ? v1 : (__expf(v1) - 1.f);
        v2 = v2 > 0.f ? v2 : (__expf(v2) - 1.f);
        v3 = v3 > 0.f ? v3 : (__expf(v3) - 1.f);
        v4 = v4 > 0.f ? v4 : (__expf(v4) - 1.f);
        v5 = v5 > 0.f ? v5 : (__expf(v5) - 1.f);
        v6 = v6 > 0.f ? v6 : (__expf(v6) - 1.f);
        v7 = v7 > 0.f ? v7 : (__expf(v7) - 1.f);
        uint4 packed;
        packed.x = (uint32)f2bf(v0) | ((uint32)f2bf(v1) << 16);
        packed.y = (uint32)f2bf(v2) | ((uint32)f2bf(v3) << 16);
        packed.z = (uint32)f2bf(v4) | ((uint32)f2bf(v5) << 16);
        packed.w = (uint32)f2bf(v6) | ((uint32)f2bf(v7) << 16);
        uint32 g = lane16 ^ ((uint32)n_local & 15u);   // swizzled granule
        *(uint4*)&ha[n_local][g * 8] = packed;
    }
    __syncthreads();

    // ---------- phase B: layer-2 transform from LDS, tt = wave id ----------
    {
        int l15 = (int)lane16, quad = (int)quarter;
        int n0 = n0blk;
        int nloc = l15;

        bf16x8 af[4];
        #pragma unroll
        for (int s = 0; s < 4; ++s) {
            uint32 g = (uint32)(s * 4 + quad) ^ (uint32)l15;
            af[s] = *(const bf16x8*)&ha[nloc][g * 8];
        }

        #pragma unroll
        for (int pass = 0; pass < 2; ++pass) {
            if (pass == 1 && w != 0) break;
            int tt = (pass == 0) ? w : 4;
            const unsigned short* Brow = (tt < 4) ? &w2t[(tt * 16 + l15) * HID]
                                                  : &p2t[l15 * HID];
            f32x4 acc = {0.f, 0.f, 0.f, 0.f};
            #pragma unroll
            for (int s = 0; s < 4; ++s) {
                bf16x8 bf = *(const bf16x8*)&Brow[s * 32 + quad * 8];
                acc = __builtin_amdgcn_mfma_f32_16x16x32_bf16(af[s], bf, acc, 0, 0, 0);
            }
            int nodeb = n0 + quad * 4;
            if (tt < 4) {
                int ch = tt * 16 + l15;
                #pragma unroll
                for (int r = 0; r < 4; ++r)
                    if (nodeb + r < N_NODES)
                        h2f[(size_t)(nodeb + r) * OUT_DIM + ch] = f2fp8(acc[r]);
            } else {
                #pragma unroll
                for (int r = 0; r < 4; ++r) {
                    if (nodeb + r < N_NODES) {
                        if (l15 == 0) a_src2[nodeb + r] = acc[r];
                        else if (l15 == 1) a_dst2[nodeb + r] = acc[r];
                    }
                }
            }
        }
    }
}

// ---------------- Layer 2: aggregate + log_softmax ----------------
// 4 nodes per wave (16 lanes/node, 4 ch/lane, fp8 uint32 gathers);
// 16 nodes/block rank-sorted by degree, 8-deep batch + index prefetch.

__global__ __launch_bounds__(256) void l2_aggregate(
        const unsigned char* __restrict__ h2f, const float* __restrict__ a_src2,
        const float* __restrict__ a_dst2, const int* __restrict__ row_start,
        const int* __restrict__ csr_src, const float* __restrict__ b2,
        float* __restrict__ out) {
    __shared__ int sdeg16[16];
    __shared__ int perm16[16];
    int t = threadIdx.x;
    int w = t >> 6;
    uint32 lane = t & 63;
    uint32 quarter = lane >> 4;
    uint32 lane16 = lane & 15;
    int nbase = blockIdx.x * 16;
    if (t < 16)
        sdeg16[t] = row_start[nbase + t + 1] - row_start[nbase + t];
    __syncthreads();
    if (t < 16) {
        int d = sdeg16[t];
        int r = 0;
        #pragma unroll
        for (int j = 0; j < 16; ++j) {
            int dj = sdeg16[j];
            r += (dj < d) || (dj == d && j < t);
        }
        perm16[r] = t;
    }
    __syncthreads();
    int n = nbase + perm16[w * 4 + (int)quarter];
    uint32 c0 = lane16 * 4u;
    int beg = row_start[n], end = row_start[n + 1];
    int cnt = end - beg;
    int kmax = cnt;
    kmax = max(kmax, __shfl_xor(kmax, 16, 64));
    kmax = max(kmax, __shfl_xor(kmax, 32, 64));
    float adst = a_dst2[n];
    float l = 0.f, a0 = 0.f, a1 = 0.f, a2 = 0.f, a3 = 0.f;

    auto edge2 = [&](float e0, uint32 u0, bool live) {
        float e = e0 + adst;
        e = fmaxf(e, NEG_SLOPE * e);
        e = live ? e : -10000.f;   // masked lane -> p = 0
        float p = exp2f(e);
        l += p;
        f32x2 f01 = __builtin_amdgcn_cvt_pk_f32_fp8((int)u0, false);
        f32x2 f23 = __builtin_amdgcn_cvt_pk_f32_fp8((int)u0, true);
        a0 = fmaf(p, f01[0], a0);
        a1 = fmaf(p, f01[1], a1);
        a2 = fmaf(p, f23[0], a2);
        a3 = fmaf(p, f23[1], a3);
    };

    int k = 0;
    uint32 ssn[8];
    if (k + 8 <= kmax) {
        #pragma unroll
        for (int q = 0; q < 8; ++q) {
            int j = beg + q;
            int jc = (j < end) ? j : (end - 1);
            ssn[q] = (uint32)csr_src[jc];
        }
    }
    for (; k + 8 <= kmax; k += 8) {
        uint32 ss[8]; float ee[8]; uint32 uu[8];
        #pragma unroll
        for (int q = 0; q < 8; ++q) ss[q] = ssn[q];
        #pragma unroll
        for (int q = 0; q < 8; ++q) ee[q] = a_src2[ss[q]];
        #pragma unroll
        for (int q = 0; q < 8; ++q) uu[q] = *(const uint32*)&h2f[(ss[q] << 6) + c0];
        int kn = k + 8;
        if (kn + 8 <= kmax) {
            #pragma unroll
            for (int q = 0; q < 8; ++q) {
                int j = beg + kn + q;
                int jc = (j < end) ? j : (end - 1);
                ssn[q] = (uint32)csr_src[jc];
            }
        }
        #pragma unroll
        for (int q = 0; q < 8; ++q) edge2(ee[q], uu[q], k + q < cnt);
    }
    for (; k < kmax; k += 4) {
        uint32 ss[4]; float ee[4]; uint32 uu[4];
        #pragma unroll
        for (int q = 0; q < 4; ++q) {
            int j = beg + k + q;
            int jc = (j < end) ? j : (end - 1);
            ss[q] = (uint32)csr_src[jc];
        }
        #pragma unroll
        for (int q = 0; q < 4; ++q) ee[q] = a_src2[ss[q]];
        #pragma unroll
        for (int q = 0; q < 4; ++q) uu[q] = *(const uint32*)&h2f[(ss[q] << 6) + c0];
        #pragma unroll
        for (int q = 0; q < 4; ++q) edge2(ee[q], uu[q], k + q < cnt);
    }

    float inv = 1.f / (l + 1e-16f);
    float o0 = a0 * inv + b2[c0 + 0];
    float o1 = a1 * inv + b2[c0 + 1];
    float o2 = a2 * inv + b2[c0 + 2];
    float o3 = a3 * inv + b2[c0 + 3];
    // log_softmax over 64 channels = 16 lanes x 4 (quarter-wave reduction)
    float mx = fmaxf(fmaxf(o0, o1), fmaxf(o2, o3));
    #pragma unroll
    for (int m = 8; m > 0; m >>= 1) mx = fmaxf(mx, __shfl_xor(mx, m, 16));
    float ex = __expf(o0 - mx) + __expf(o1 - mx) + __expf(o2 - mx) + __expf(o3 - mx);
    #pragma unroll
    for (int m = 8; m > 0; m >>= 1) ex += __shfl_xor(ex, m, 16);
    float lse = mx + __logf(ex);
    float4 o = make_float4(o0 - lse, o1 - lse, o2 - lse, o3 - lse);
    *(float4*)&out[(size_t)n * OUT_DIM + c0] = o;
}

// ---------------- launch ----------------

extern "C" void kernel_launch(void* const* d_in, const int* in_sizes, int n_in,
                              void* d_out, int out_size, void* d_ws, size_t ws_size,
                              hipStream_t stream) {
    const float* x   = (const float*)d_in[0];
    const int*   ei  = (const int*)d_in[1];
    const float* W1  = (const float*)d_in[2];
    const float* as1 = (const float*)d_in[3];
    const float* ad1 = (const float*)d_in[4];
    const float* b1  = (const float*)d_in[5];
    const float* W2  = (const float*)d_in[6];
    const float* as2 = (const float*)d_in[7];
    const float* ad2 = (const float*)d_in[8];
    const float* b2  = (const float*)d_in[9];
    float* out = (float*)d_out;

    const int* src = ei;             // row 0
    const int* dst = ei + E_EDGES;   // row 1

    char* ws = (char*)d_ws;
    size_t off = 0;
    auto alloc = [&](size_t bytes) -> void* {
        void* p = ws + off;
        off += (bytes + 255) & ~size_t(255);
        return p;
    };
    unsigned char*  h1f    = (unsigned char*)alloc((size_t)N_NODES * HID);
    unsigned char*  h2f    = (unsigned char*)alloc((size_t)N_NODES * OUT_DIM);
    unsigned short* w1t    = (unsigned short*)alloc((size_t)HID * IN_DIM * 2);
    unsigned short* p1t    = (unsigned short*)alloc((size_t)16 * IN_DIM * 2);
    unsigned short* w2t    = (unsigned short*)alloc((size_t)OUT_DIM * HID * 2);
    unsigned short* p2t    = (unsigned short*)alloc((size_t)16 * HID * 2);
    float* a_src1    = (float*)alloc((size_t)N_NODES * HEADS * 4);
    float* a_dst1    = (float*)alloc((size_t)N_NODES * HEADS * 4);
    float* a_src2    = (float*)alloc((size_t)N_NODES * 4);
    float* a_dst2    = (float*)alloc((size_t)N_NODES * 4);
    int*   row_start = (int*)alloc((size_t)(N_NODES + 1) * 4);
    int*   csr_src   = (int*)alloc((size_t)ET * 4);
    uint32* pairs    = (uint32*)alloc((size_t)ET * 4);
    int*   cnt       = (int*)alloc((size_t)NB * NT * 4);
    int*   bucketStart = (int*)alloc((size_t)(NB + 1) * 4);

    prep_all<<<MEGA_A, 256, 0, stream>>>(dst, cnt, W1, as1, ad1,
                                         W2, as2, ad2, w1t, p1t, w2t, p2t);
    scatter_l1ta<<<NT + L1TA, 256, 0, stream>>>(src, dst, cnt, bucketStart, pairs,
                                                x, w1t, p1t, h1f, a_src1, a_dst1);
    bucket_l1tb<<<NB + L1TB, 256, 0, stream>>>(pairs, bucketStart, row_start, csr_src,
                                               x, w1t, p1t, h1f, a_src1, a_dst1);
    l1agg_l2t<<<FUSE_BLOCKS, 256, 0, stream>>>(h1f, a_src1, a_dst1, row_start, csr_src,
                                               b1, w2t, p2t, h2f, a_src2, a_dst2);
    l2_aggregate<<<FUSE_BLOCKS, 256, 0, stream>>>(h2f, a_src2, a_dst2, row_start,
                                                  csr_src, b2, out);
}

// Round 6
// 186.410 us; speedup vs baseline: 1.3877x; 1.0096x over previous
//
#include <hip/hip_runtime.h>
#include <math.h>

#define N_NODES 50000
#define E_EDGES 800000
#define ET      (E_EDGES + N_NODES)   // edges + self loops
#define IN_DIM  128
#define HID     128
#define HEADS   8
#define C1      16
#define OUT_DIM 64
#define NEG_SLOPE 0.2f
#define LOG2E   1.4426950408889634f

#define TILE    8192
#define NT      ((ET + TILE - 1) / TILE)      // 104 tiles
#define NB      ((N_NODES + 255) / 256)       // 196 buckets of 256 nodes

#define PREP_BLOCKS 112
#define MEGA_A (NT + PREP_BLOCKS)             // 216
#define L1T_BLOCKS ((N_NODES + 63) / 64)      // 782
#define L1TA 391                              // l1-transform blocks in K2
#define L1TB (L1T_BLOCKS - L1TA)              // remainder in K3
#define FUSE_BLOCKS ((N_NODES + 15) / 16)     // 3125
#define L2_BLOCKS   ((N_NODES + 31) / 32)     // 1563 (32 nodes/block)

typedef unsigned int uint32;
typedef __attribute__((ext_vector_type(8))) short bf16x8;
typedef __attribute__((ext_vector_type(4))) float f32x4;
typedef __attribute__((ext_vector_type(2))) float f32x2;

static __device__ __forceinline__ unsigned short f2bf(float f) {
    uint32 u = __float_as_uint(f);
    u += 0x7FFFu + ((u >> 16) & 1u);   // round to nearest even
    return (unsigned short)(u >> 16);
}

static __device__ __forceinline__ unsigned char f2fp8(float f) {
    int pk = __builtin_amdgcn_cvt_pk_fp8_f32(f, f, 0, false);   // RNE, OCP e4m3
    return (unsigned char)(pk & 0xFF);
}

// ---------------- Mega-kernel A: bucket_hist + prep_weights ----------------
// (x conversion is done inline in the l1 transform — no xb pass)

__global__ __launch_bounds__(256) void prep_all(
        const int* __restrict__ dst, int* __restrict__ cnt,
        const float* __restrict__ W1, const float* __restrict__ as1,
        const float* __restrict__ ad1, const float* __restrict__ W2,
        const float* __restrict__ as2, const float* __restrict__ ad2,
        unsigned short* __restrict__ w1t, unsigned short* __restrict__ p1t,
        unsigned short* __restrict__ w2t, unsigned short* __restrict__ p2t) {
    __shared__ int hist[NB];
    int blk = blockIdx.x, t = threadIdx.x;
    if (blk < NT) {
        for (int b = t; b < NB; b += 256) hist[b] = 0;
        __syncthreads();
        int base = blk * TILE;
        #pragma unroll
        for (int it = 0; it < TILE / 256; ++it) {
            int i = base + it * 256 + t;
            if (i < ET) {
                int d = (i < E_EDGES) ? dst[i] : (i - E_EDGES);
                atomicAdd(&hist[d >> 8], 1);
            }
        }
        __syncthreads();
        for (int b = t; b < NB; b += 256) cnt[blk * NB + b] = hist[b];
    } else {
        int b = blk - NT;    // 0..111
        if (b < 64) {
            int i = b * 256 + t;                // n*128+k
            int n = i >> 7, k = i & 127;
            w1t[n * IN_DIM + k] = f2bf(W1[k * HID + n]);
        } else if (b < 96) {
            int i = (b - 64) * 256 + t;         // n*128+k, n<64
            int n = i >> 7, k = i & 127;
            w2t[n * HID + k] = f2bf(W2[k * OUT_DIM + n]);
        } else if (b < 104) {
            int i = (b - 96) * 256 + t;         // j*128+k, j<16
            int j = i >> 7, k = i & 127;
            int hh = j & 7;
            const float* a = (j < 8) ? as1 : ad1;
            float acc = 0.f;
            #pragma unroll
            for (int c = 0; c < C1; ++c)
                acc = fmaf(W1[k * HID + hh * C1 + c], a[hh * C1 + c], acc);
            p1t[j * IN_DIM + k] = f2bf(acc * LOG2E);
        } else {
            int i = (b - 104) * 256 + t;        // j*128+k, j<16
            int j = i >> 7, k = i & 127;
            if (j < 2) {
                const float* a = (j == 0) ? as2 : ad2;
                float acc = 0.f;
                #pragma unroll
                for (int c = 0; c < OUT_DIM; ++c)
                    acc = fmaf(W2[k * OUT_DIM + c], a[c], acc);
                p2t[j * HID + k] = f2bf(acc * LOG2E);
            } else {
                p2t[j * HID + k] = 0;
            }
        }
    }
}

// ---------------- layer-1 transform body (MFMA, LDS-free) — shared by K2/K3 ----------------
// A-fragment: reads x in f32 and converts to bf16 in-register (same RNE).
// h1 payload stored as fp8 e4m3: 128 B/node.

static __device__ __forceinline__ void l1_transform_body(
        int bb, int t,
        const float* __restrict__ x, const unsigned short* __restrict__ w1t,
        const unsigned short* __restrict__ p1t, unsigned char* __restrict__ h1f,
        float* __restrict__ a_src, float* __restrict__ a_dst) {
    int w = t >> 6, lane = t & 63;
    int l15 = lane & 15, quad = lane >> 4;
    int n0 = bb * 64 + w * 16;
    int mrow = n0 + l15;
    int mload = (mrow < N_NODES) ? mrow : (N_NODES - 1);

    bf16x8 af[4];
    #pragma unroll
    for (int s = 0; s < 4; ++s) {
        const float* xr = &x[(size_t)mload * IN_DIM + s * 32 + quad * 8];
        float4 lo = *(const float4*)xr;
        float4 hi = *(const float4*)(xr + 4);
        bf16x8 v;
        v[0] = (short)f2bf(lo.x); v[1] = (short)f2bf(lo.y);
        v[2] = (short)f2bf(lo.z); v[3] = (short)f2bf(lo.w);
        v[4] = (short)f2bf(hi.x); v[5] = (short)f2bf(hi.y);
        v[6] = (short)f2bf(hi.z); v[7] = (short)f2bf(hi.w);
        af[s] = v;
    }

    #pragma unroll
    for (int tt = 0; tt < 9; ++tt) {
        const unsigned short* Brow = (tt < 8) ? &w1t[(tt * 16 + l15) * IN_DIM]
                                              : &p1t[l15 * IN_DIM];
        f32x4 acc = {0.f, 0.f, 0.f, 0.f};
        #pragma unroll
        for (int s = 0; s < 4; ++s) {
            bf16x8 bf = *(const bf16x8*)&Brow[s * 32 + quad * 8];
            acc = __builtin_amdgcn_mfma_f32_16x16x32_bf16(af[s], bf, acc, 0, 0, 0);
        }
        int nodeb = n0 + quad * 4;
        if (tt < 8) {
            int ch = tt * 16 + l15;
            #pragma unroll
            for (int r = 0; r < 4; ++r)
                if (nodeb + r < N_NODES)
                    h1f[(size_t)(nodeb + r) * HID + ch] = f2fp8(acc[r]);
        } else {
            #pragma unroll
            for (int r = 0; r < 4; ++r) {
                if (nodeb + r < N_NODES) {
                    if (l15 < 8) a_src[(nodeb + r) * HEADS + l15] = acc[r];
                    else         a_dst[(nodeb + r) * HEADS + (l15 - 8)] = acc[r];
                }
            }
        }
    }
}

// ---------------- K2: bucket_scatter (scan fused) + l1-transform part A ----------------

__global__ __launch_bounds__(256) void scatter_l1ta(
        const int* __restrict__ src, const int* __restrict__ dst,
        const int* __restrict__ cnt, int* __restrict__ bucketStart,
        uint32* __restrict__ pairs,
        const float* __restrict__ x, const unsigned short* __restrict__ w1t,
        const unsigned short* __restrict__ p1t, unsigned char* __restrict__ h1f,
        float* __restrict__ a_src, float* __restrict__ a_dst) {
    __shared__ int lcur[NB];
    __shared__ int sscan[256];
    int t = threadIdx.x;
    if (blockIdx.x >= NT) {
        l1_transform_body(blockIdx.x - NT, t, x, w1t, p1t, h1f, a_src, a_dst);
        return;
    }
    int tile = blockIdx.x;

    int run = 0, total = 0;
    if (t < NB) {
        for (int k = 0; k < NT; ++k) {
            int c = cnt[k * NB + t];     // coalesced across t
            if (k < tile) run += c;
            total += c;
        }
    }
    sscan[t] = (t < NB) ? total : 0;
    __syncthreads();
    #pragma unroll
    for (int off = 1; off < 256; off <<= 1) {
        int add = (t >= off) ? sscan[t - off] : 0;
        __syncthreads();
        sscan[t] += add;
        __syncthreads();
    }
    int bstart = sscan[t] - total;       // exclusive prefix
    if (t < NB) {
        lcur[t] = bstart + run;
        if (tile == 0) bucketStart[t] = bstart;
    }
    if (tile == 0 && t == 0) bucketStart[NB] = ET;
    __syncthreads();

    int base = tile * TILE;
    #pragma unroll
    for (int it = 0; it < TILE / 256; ++it) {
        int i = base + it * 256 + t;
        if (i < ET) {
            int s, d;
            if (i < E_EDGES) { s = src[i]; d = dst[i]; }
            else             { s = d = i - E_EDGES; }
            int pos = atomicAdd(&lcur[d >> 8], 1);
            pairs[pos] = ((uint32)s << 8) | (uint32)(d & 255);
        }
    }
}

// ---------------- K3: bucket_build + l1-transform part B ----------------

__global__ __launch_bounds__(256) void bucket_l1tb(
        const uint32* __restrict__ pairs, const int* __restrict__ bucketStart,
        int* __restrict__ row_start, int* __restrict__ csr_src,
        const float* __restrict__ x, const unsigned short* __restrict__ w1t,
        const unsigned short* __restrict__ p1t, unsigned char* __restrict__ h1f,
        float* __restrict__ a_src, float* __restrict__ a_dst) {
    __shared__ int sdeg[256];
    __shared__ int sscan[256];
    int t = threadIdx.x;
    if (blockIdx.x >= NB) {
        l1_transform_body(blockIdx.x - NB + L1TA, t, x, w1t, p1t, h1f, a_src, a_dst);
        return;
    }
    int b = blockIdx.x;
    int beg = bucketStart[b], end = bucketStart[b + 1];
    sdeg[t] = 0;
    __syncthreads();
    for (int j = beg + t; j < end; j += 256)
        atomicAdd(&sdeg[pairs[j] & 255u], 1);
    __syncthreads();
    int v = sdeg[t];
    sscan[t] = v;
    __syncthreads();
    #pragma unroll
    for (int off = 1; off < 256; off <<= 1) {
        int add = (t >= off) ? sscan[t - off] : 0;
        __syncthreads();
        sscan[t] += add;
        __syncthreads();
    }
    int pos0 = beg + sscan[t] - v;   // exclusive prefix within bucket
    int n = b * 256 + t;
    if (n < N_NODES) row_start[n] = pos0;
    if (b == 0 && t == 0) row_start[N_NODES] = ET;
    __syncthreads();
    sscan[t] = pos0;                 // reuse as cursor
    __syncthreads();
    for (int j = beg + t; j < end; j += 256) {
        uint32 p = pairs[j];
        int pos = atomicAdd(&sscan[p & 255u], 1);
        csr_src[pos] = (int)(p >> 8);
    }
}

// ---------------- Fused: layer-1 aggregate + layer-2 transform ----------------
// 256-thread block (4 waves) on a 16-node tile: phase A = ONE pass/wave
// (4 rank-adjacent nodes, 16 lanes/node, fp8 uint2 gathers, 8-deep batch,
// one-deep csr_src index prefetch — keeps live VGPRs <=128 for 4 waves/SIMD).
// Phase B: wave w does output tile tt=w (h2 stored fp8), wave 0 also tt=4.

__global__ __launch_bounds__(256, 4) void l1agg_l2t(
        const unsigned char* __restrict__ h1f, const float* __restrict__ a_src,
        const float* __restrict__ a_dst, const int* __restrict__ row_start,
        const int* __restrict__ csr_src, const float* __restrict__ b1,
        const unsigned short* __restrict__ w2t, const unsigned short* __restrict__ p2t,
        unsigned char* __restrict__ h2f, float* __restrict__ a_src2,
        float* __restrict__ a_dst2) {
    __shared__ unsigned short ha[16][128];   // 4 KB, swizzled granules
    __shared__ int sdeg16[16];
    __shared__ unsigned char perm[16];
    int t = threadIdx.x;
    int w = t >> 6;              // 0..3
    uint32 lane = t & 63;
    uint32 quarter = lane >> 4;
    uint32 lane16 = lane & 15;
    int n0blk = blockIdx.x * 16;

    // ---- degree-rank the 16 nodes (once per block) ----
    if (t < 16) {
        int n = n0blk + t;
        int nc = (n < N_NODES) ? n : (N_NODES - 1);
        sdeg16[t] = row_start[nc + 1] - row_start[nc];
    }
    __syncthreads();
    if (t < 16) {
        int d = sdeg16[t];
        int r = 0;
        #pragma unroll
        for (int j = 0; j < 16; ++j) {
            int dj = sdeg16[j];
            r += (dj < d) || (dj == d && j < t);
        }
        perm[r] = (unsigned char)t;
    }
    __syncthreads();

    // ---------- phase A: 4 waves x 4 nodes, one pass ----------
    {
        uint32 c0 = lane16 * 8u;     // 8 channels per lane (8 fp8 bytes)
        uint32 h = lane16 >> 1;      // head = c0 >> 4
        int n_local = (int)perm[w * 4 + (int)quarter];
        int n = n0blk + n_local;
        int nc = (n < N_NODES) ? n : (N_NODES - 1);
        int beg = row_start[nc], end = row_start[nc + 1];
        int cnt = end - beg;
        int kmax = cnt;
        kmax = max(kmax, __shfl_xor(kmax, 16, 64));
        kmax = max(kmax, __shfl_xor(kmax, 32, 64));
        float adst = a_dst[nc * HEADS + h];
        float l = 0.f;
        float a0 = 0.f, a1 = 0.f, a2 = 0.f, a3 = 0.f;
        float a4 = 0.f, a5 = 0.f, a6 = 0.f, a7 = 0.f;

        auto edge = [&](float e0, uint2 u0, bool live) {
            float e = e0 + adst;
            e = fmaxf(e, NEG_SLOPE * e);          // leaky relu (log2 domain)
            e = live ? e : -10000.f;              // masked lane -> p = 0
            float p = exp2f(e);
            l += p;
            f32x2 f01 = __builtin_amdgcn_cvt_pk_f32_fp8((int)u0.x, false);
            f32x2 f23 = __builtin_amdgcn_cvt_pk_f32_fp8((int)u0.x, true);
            f32x2 f45 = __builtin_amdgcn_cvt_pk_f32_fp8((int)u0.y, false);
            f32x2 f67 = __builtin_amdgcn_cvt_pk_f32_fp8((int)u0.y, true);
            a0 = fmaf(p, f01[0], a0);
            a1 = fmaf(p, f01[1], a1);
            a2 = fmaf(p, f23[0], a2);
            a3 = fmaf(p, f23[1], a3);
            a4 = fmaf(p, f45[0], a4);
            a5 = fmaf(p, f45[1], a5);
            a6 = fmaf(p, f67[0], a6);
            a7 = fmaf(p, f67[1], a7);
        };

        int k = 0;
        uint32 ssn[8];
        if (k + 8 <= kmax) {
            #pragma unroll
            for (int q = 0; q < 8; ++q) {
                int j = beg + q;
                int jc = (j < end) ? j : (end - 1);    // cnt >= 1 (self loop)
                ssn[q] = (uint32)csr_src[jc];
            }
        }
        for (; k + 8 <= kmax; k += 8) {
            uint32 ss[8]; float ee[8]; uint2 uu[8];
            #pragma unroll
            for (int q = 0; q < 8; ++q) ss[q] = ssn[q];
            // indices already in regs -> gathers issue immediately
            #pragma unroll
            for (int q = 0; q < 8; ++q) ee[q] = a_src[ss[q] * 8u + h];
            #pragma unroll
            for (int q = 0; q < 8; ++q) uu[q] = *(const uint2*)&h1f[(ss[q] << 7) + c0];
            // prefetch next batch's indices under this batch's compute
            int kn = k + 8;
            if (kn + 8 <= kmax) {
                #pragma unroll
                for (int q = 0; q < 8; ++q) {
                    int j = beg + kn + q;
                    int jc = (j < end) ? j : (end - 1);
                    ssn[q] = (uint32)csr_src[jc];
                }
            }
            #pragma unroll
            for (int q = 0; q < 8; ++q) edge(ee[q], uu[q], k + q < cnt);
        }
        for (; k < kmax; k += 4) {
            uint32 ss[4]; float ee[4]; uint2 uu[4];
            #pragma unroll
            for (int q = 0; q < 4; ++q) {
                int j = beg + k + q;
                int jc = (j < end) ? j : (end - 1);
                ss[q] = (uint32)csr_src[jc];
            }
            #pragma unroll
            for (int q = 0; q < 4; ++q) ee[q] = a_src[ss[q] * 8u + h];
            #pragma unroll
            for (int q = 0; q < 4; ++q) uu[q] = *(const uint2*)&h1f[(ss[q] << 7) + c0];
            #pragma unroll
            for (int q = 0; q < 4; ++q) edge(ee[q], uu[q], k + q < cnt);
        }

        float inv = 1.f / (l + 1e-16f);
        float v0 = a0 * inv + b1[c0 + 0];
        float v1 = a1 * inv + b1[c0 + 1];
        float v2 = a2 * inv + b1[c0 + 2];
        float v3 = a3 * inv + b1[c0 + 3];
        float v4 = a4 * inv + b1[c0 + 4];
        float v5 = a5 * inv + b1[c0 + 5];
        float v6 = a6 * inv + b1[c0 + 6];
        float v7 = a7 * inv + b1[c0 + 7];
        v0 = v0 > 0.f ? v0 : (__expf(v0) - 1.f);   // ELU
        v1 = v1 > 0.f ? v1 : (__expf(v1) - 1.f);
        v2 = v2 > 0.f ? v2 : (__expf(v2) - 1.f);
        v3 = v3 > 0.f ? v3 : (__expf(v3) - 1.f);
        v4 = v4 > 0.f ? v4 : (__expf(v4) - 1.f);
        v5 = v5 > 0.f ? v5 : (__expf(v5) - 1.f);
        v6 = v6 > 0.f ? v6 : (__expf(v6) - 1.f);
        v7 = v7 > 0.f ? v7 : (__expf(v7) - 1.f);
        uint4 packed;
        packed.x = (uint32)f2bf(v0) | ((uint32)f2bf(v1) << 16);
        packed.y = (uint32)f2bf(v2) | ((uint32)f2bf(v3) << 16);
        packed.z = (uint32)f2bf(v4) | ((uint32)f2bf(v5) << 16);
        packed.w = (uint32)f2bf(v6) | ((uint32)f2bf(v7) << 16);
        uint32 g = lane16 ^ ((uint32)n_local & 15u);   // swizzled granule
        *(uint4*)&ha[n_local][g * 8] = packed;
    }
    __syncthreads();

    // ---------- phase B: layer-2 transform from LDS, tt = wave id ----------
    {
        int l15 = (int)lane16, quad = (int)quarter;
        int n0 = n0blk;
        int nloc = l15;

        bf16x8 af[4];
        #pragma unroll
        for (int s = 0; s < 4; ++s) {
            uint32 g = (uint32)(s * 4 + quad) ^ (uint32)l15;
            af[s] = *(const bf16x8*)&ha[nloc][g * 8];
        }

        #pragma unroll
        for (int pass = 0; pass < 2; ++pass) {
            if (pass == 1 && w != 0) break;
            int tt = (pass == 0) ? w : 4;
            const unsigned short* Brow = (tt < 4) ? &w2t[(tt * 16 + l15) * HID]
                                                  : &p2t[l15 * HID];
            f32x4 acc = {0.f, 0.f, 0.f, 0.f};
            #pragma unroll
            for (int s = 0; s < 4; ++s) {
                bf16x8 bf = *(const bf16x8*)&Brow[s * 32 + quad * 8];
                acc = __builtin_amdgcn_mfma_f32_16x16x32_bf16(af[s], bf, acc, 0, 0, 0);
            }
            int nodeb = n0 + quad * 4;
            if (tt < 4) {
                int ch = tt * 16 + l15;
                #pragma unroll
                for (int r = 0; r < 4; ++r)
                    if (nodeb + r < N_NODES)
                        h2f[(size_t)(nodeb + r) * OUT_DIM + ch] = f2fp8(acc[r]);
            } else {
                #pragma unroll
                for (int r = 0; r < 4; ++r) {
                    if (nodeb + r < N_NODES) {
                        if (l15 == 0) a_src2[nodeb + r] = acc[r];
                        else if (l15 == 1) a_dst2[nodeb + r] = acc[r];
                    }
                }
            }
        }
    }
}

// ---------------- Layer 2: aggregate + log_softmax ----------------
// Widened to l1agg's proven-healthy gather shape: 8 lanes/node, 8 ch/lane
// (uint2 fp8 gathers -> one wave-load covers 8 edges), 8 accumulators.
// 32 nodes/block (4 waves x 8 nodes) rank-sorted; 8-deep batch + index prefetch.

__global__ __launch_bounds__(256, 4) void l2_aggregate(
        const unsigned char* __restrict__ h2f, const float* __restrict__ a_src2,
        const float* __restrict__ a_dst2, const int* __restrict__ row_start,
        const int* __restrict__ csr_src, const float* __restrict__ b2,
        float* __restrict__ out) {
    __shared__ int sdeg32[32];
    __shared__ unsigned char perm[32];
    int t = threadIdx.x;
    int w = t >> 6;
    uint32 lane = t & 63;
    uint32 oct = lane >> 3;      // 0..7 node slot within wave
    uint32 lane8 = lane & 7;     // channel slot (8 ch each)
    int nbase = blockIdx.x * 32;
    if (t < 32) {
        int n = nbase + t;
        int nc = (n < N_NODES) ? n : (N_NODES - 1);
        sdeg32[t] = row_start[nc + 1] - row_start[nc];
    }
    __syncthreads();
    if (t < 32) {
        int d = sdeg32[t];
        int r = 0;
        #pragma unroll
        for (int j = 0; j < 32; ++j) {
            int dj = sdeg32[j];
            r += (dj < d) || (dj == d && j < t);
        }
        perm[r] = (unsigned char)t;
    }
    __syncthreads();
    int n = nbase + (int)perm[w * 8 + (int)oct];
    int nc = (n < N_NODES) ? n : (N_NODES - 1);
    uint32 c0 = lane8 * 8u;      // 8 fp8 channels per lane
    int beg = row_start[nc], end = row_start[nc + 1];
    int cnt = end - beg;
    int kmax = cnt;
    kmax = max(kmax, __shfl_xor(kmax, 8, 64));
    kmax = max(kmax, __shfl_xor(kmax, 16, 64));
    kmax = max(kmax, __shfl_xor(kmax, 32, 64));
    float adst = a_dst2[nc];
    float l = 0.f;
    float a0 = 0.f, a1 = 0.f, a2 = 0.f, a3 = 0.f;
    float a4 = 0.f, a5 = 0.f, a6 = 0.f, a7 = 0.f;

    auto edge2 = [&](float e0, uint2 u0, bool live) {
        float e = e0 + adst;
        e = fmaxf(e, NEG_SLOPE * e);
        e = live ? e : -10000.f;   // masked lane -> p = 0
        float p = exp2f(e);
        l += p;
        f32x2 f01 = __builtin_amdgcn_cvt_pk_f32_fp8((int)u0.x, false);
        f32x2 f23 = __builtin_amdgcn_cvt_pk_f32_fp8((int)u0.x, true);
        f32x2 f45 = __builtin_amdgcn_cvt_pk_f32_fp8((int)u0.y, false);
        f32x2 f67 = __builtin_amdgcn_cvt_pk_f32_fp8((int)u0.y, true);
        a0 = fmaf(p, f01[0], a0);
        a1 = fmaf(p, f01[1], a1);
        a2 = fmaf(p, f23[0], a2);
        a3 = fmaf(p, f23[1], a3);
        a4 = fmaf(p, f45[0], a4);
        a5 = fmaf(p, f45[1], a5);
        a6 = fmaf(p, f67[0], a6);
        a7 = fmaf(p, f67[1], a7);
    };

    int k = 0;
    uint32 ssn[8];
    if (k + 8 <= kmax) {
        #pragma unroll
        for (int q = 0; q < 8; ++q) {
            int j = beg + q;
            int jc = (j < end) ? j : (end - 1);
            ssn[q] = (uint32)csr_src[jc];
        }
    }
    for (; k + 8 <= kmax; k += 8) {
        uint32 ss[8]; float ee[8]; uint2 uu[8];
        #pragma unroll
        for (int q = 0; q < 8; ++q) ss[q] = ssn[q];
        #pragma unroll
        for (int q = 0; q < 8; ++q) ee[q] = a_src2[ss[q]];
        #pragma unroll
        for (int q = 0; q < 8; ++q) uu[q] = *(const uint2*)&h2f[(ss[q] << 6) + c0];
        int kn = k + 8;
        if (kn + 8 <= kmax) {
            #pragma unroll
            for (int q = 0; q < 8; ++q) {
                int j = beg + kn + q;
                int jc = (j < end) ? j : (end - 1);
                ssn[q] = (uint32)csr_src[jc];
            }
        }
        #pragma unroll
        for (int q = 0; q < 8; ++q) edge2(ee[q], uu[q], k + q < cnt);
    }
    for (; k < kmax; k += 4) {
        uint32 ss[4]; float ee[4]; uint2 uu[4];
        #pragma unroll
        for (int q = 0; q < 4; ++q) {
            int j = beg + k + q;
            int jc = (j < end) ? j : (end - 1);
            ss[q] = (uint32)csr_src[jc];
        }
        #pragma unroll
        for (int q = 0; q < 4; ++q) ee[q] = a_src2[ss[q]];
        #pragma unroll
        for (int q = 0; q < 4; ++q) uu[q] = *(const uint2*)&h2f[(ss[q] << 6) + c0];
        #pragma unroll
        for (int q = 0; q < 4; ++q) edge2(ee[q], uu[q], k + q < cnt);
    }

    float inv = 1.f / (l + 1e-16f);
    float o0 = a0 * inv + b2[c0 + 0];
    float o1 = a1 * inv + b2[c0 + 1];
    float o2 = a2 * inv + b2[c0 + 2];
    float o3 = a3 * inv + b2[c0 + 3];
    float o4 = a4 * inv + b2[c0 + 4];
    float o5 = a5 * inv + b2[c0 + 5];
    float o6 = a6 * inv + b2[c0 + 6];
    float o7 = a7 * inv + b2[c0 + 7];
    // log_softmax over 64 channels = 8 lanes x 8 (eighth-wave reduction)
    float mx = fmaxf(fmaxf(fmaxf(o0, o1), fmaxf(o2, o3)),
                     fmaxf(fmaxf(o4, o5), fmaxf(o6, o7)));
    #pragma unroll
    for (int m = 4; m > 0; m >>= 1) mx = fmaxf(mx, __shfl_xor(mx, m, 8));
    float ex = __expf(o0 - mx) + __expf(o1 - mx) + __expf(o2 - mx) + __expf(o3 - mx)
             + __expf(o4 - mx) + __expf(o5 - mx) + __expf(o6 - mx) + __expf(o7 - mx);
    #pragma unroll
    for (int m = 4; m > 0; m >>= 1) ex += __shfl_xor(ex, m, 8);
    float lse = mx + __logf(ex);
    if (n < N_NODES) {
        float4 oa = make_float4(o0 - lse, o1 - lse, o2 - lse, o3 - lse);
        float4 ob = make_float4(o4 - lse, o5 - lse, o6 - lse, o7 - lse);
        *(float4*)&out[(size_t)n * OUT_DIM + c0] = oa;
        *(float4*)&out[(size_t)n * OUT_DIM + c0 + 4] = ob;
    }
}

// ---------------- launch ----------------

extern "C" void kernel_launch(void* const* d_in, const int* in_sizes, int n_in,
                              void* d_out, int out_size, void* d_ws, size_t ws_size,
                              hipStream_t stream) {
    const float* x   = (const float*)d_in[0];
    const int*   ei  = (const int*)d_in[1];
    const float* W1  = (const float*)d_in[2];
    const float* as1 = (const float*)d_in[3];
    const float* ad1 = (const float*)d_in[4];
    const float* b1  = (const float*)d_in[5];
    const float* W2  = (const float*)d_in[6];
    const float* as2 = (const float*)d_in[7];
    const float* ad2 = (const float*)d_in[8];
    const float* b2  = (const float*)d_in[9];
    float* out = (float*)d_out;

    const int* src = ei;             // row 0
    const int* dst = ei + E_EDGES;   // row 1

    char* ws = (char*)d_ws;
    size_t off = 0;
    auto alloc = [&](size_t bytes) -> void* {
        void* p = ws + off;
        off += (bytes + 255) & ~size_t(255);
        return p;
    };
    unsigned char*  h1f    = (unsigned char*)alloc((size_t)N_NODES * HID);
    unsigned char*  h2f    = (unsigned char*)alloc((size_t)N_NODES * OUT_DIM);
    unsigned short* w1t    = (unsigned short*)alloc((size_t)HID * IN_DIM * 2);
    unsigned short* p1t    = (unsigned short*)alloc((size_t)16 * IN_DIM * 2);
    unsigned short* w2t    = (unsigned short*)alloc((size_t)OUT_DIM * HID * 2);
    unsigned short* p2t    = (unsigned short*)alloc((size_t)16 * HID * 2);
    float* a_src1    = (float*)alloc((size_t)N_NODES * HEADS * 4);
    float* a_dst1    = (float*)alloc((size_t)N_NODES * HEADS * 4);
    float* a_src2    = (float*)alloc((size_t)N_NODES * 4);
    float* a_dst2    = (float*)alloc((size_t)N_NODES * 4);
    int*   row_start = (int*)alloc((size_t)(N_NODES + 1) * 4);
    int*   csr_src   = (int*)alloc((size_t)ET * 4);
    uint32* pairs    = (uint32*)alloc((size_t)ET * 4);
    int*   cnt       = (int*)alloc((size_t)NB * NT * 4);
    int*   bucketStart = (int*)alloc((size_t)(NB + 1) * 4);

    prep_all<<<MEGA_A, 256, 0, stream>>>(dst, cnt, W1, as1, ad1,
                                         W2, as2, ad2, w1t, p1t, w2t, p2t);
    scatter_l1ta<<<NT + L1TA, 256, 0, stream>>>(src, dst, cnt, bucketStart, pairs,
                                                x, w1t, p1t, h1f, a_src1, a_dst1);
    bucket_l1tb<<<NB + L1TB, 256, 0, stream>>>(pairs, bucketStart, row_start, csr_src,
                                               x, w1t, p1t, h1f, a_src1, a_dst1);
    l1agg_l2t<<<FUSE_BLOCKS, 256, 0, stream>>>(h1f, a_src1, a_dst1, row_start, csr_src,
                                               b1, w2t, p2t, h2f, a_src2, a_dst2);
    l2_aggregate<<<L2_BLOCKS, 256, 0, stream>>>(h2f, a_src2, a_dst2, row_start,
                                                csr_src, b2, out);
}